// Round 4
// baseline (814.631 us; speedup 1.0000x reference)
//
#include <hip/hip_runtime.h>
#include <cstddef>

#define NN 50000
#define NE 800000
#define HCH 256     // H*C
#define MPAD 50048  // 391*128 = 782*64

typedef __attribute__((ext_vector_type(4))) float f32x4;
typedef __attribute__((ext_vector_type(8))) short s16x8;
typedef __attribute__((ext_vector_type(8))) unsigned short u16x8;
typedef unsigned int uint32;

__device__ inline float bf2f(unsigned short u) {
    return __uint_as_float(((unsigned int)u) << 16);
}
__device__ inline unsigned short f2bf(float f) {
    unsigned int x = __float_as_uint(f);
    x += 0x7FFFu + ((x >> 16) & 1u);   // round to nearest even
    return (unsigned short)(x >> 16);
}

// ---------------- CSR build ----------------
__global__ void k_zero(int* __restrict__ p, int n) {
    int i = blockIdx.x * blockDim.x + threadIdx.x;
    if (i < n) p[i] = 0;
}

__global__ void k_hist(const int* __restrict__ dst, int* __restrict__ deg, int e) {
    int i = blockIdx.x * blockDim.x + threadIdx.x;
    if (i < e) atomicAdd(&deg[dst[i]], 1);
}

__global__ __launch_bounds__(1024) void k_scan_a(const int* __restrict__ deg,
                                                 int* __restrict__ incl,
                                                 int* __restrict__ btot, int n) {
    __shared__ int buf[1024];
    int t = threadIdx.x;
    int i = blockIdx.x * 1024 + t;
    int v = (i < n) ? deg[i] : 0;
    buf[t] = v;
    __syncthreads();
    #pragma unroll
    for (int s = 1; s < 1024; s <<= 1) {
        int tv = (t >= s) ? buf[t - s] : 0;
        __syncthreads();
        buf[t] += tv;
        __syncthreads();
    }
    if (i < n) incl[i] = buf[t];
    if (t == 1023) btot[blockIdx.x] = buf[1023];
}

__global__ void k_scan_b(const int* __restrict__ btot, int* __restrict__ bbase, int nb) {
    if (threadIdx.x == 0 && blockIdx.x == 0) {
        int s = 0;
        for (int b = 0; b < nb; ++b) { bbase[b] = s; s += btot[b]; }
    }
}

__global__ __launch_bounds__(1024) void k_scan_c(const int* __restrict__ deg,
                                                 const int* __restrict__ incl,
                                                 const int* __restrict__ bbase,
                                                 int* __restrict__ off,
                                                 int* __restrict__ cur, int n) {
    int i = blockIdx.x * 1024 + threadIdx.x;
    if (i < n) {
        int inc = bbase[blockIdx.x] + incl[i];
        off[i + 1] = inc;
        cur[i] = inc - deg[i];
    }
    if (i == 0) off[0] = 0;
}

__global__ void k_scatter(const int* __restrict__ src, const int* __restrict__ dst,
                          const float* __restrict__ attr, int* __restrict__ cur,
                          int2* __restrict__ csr, int e) {
    int i = blockIdx.x * blockDim.x + threadIdx.x;
    if (i < e) {
        int d = dst[i];
        int pos = atomicAdd(&cur[d], 1);
        csr[pos] = make_int2(src[i], __float_as_int(attr[i]));
    }
}

// ---------------- fused weight pack: all 8 layer mats + classifier W1 ----------------
// Bt layout: [layer*4 + mat][256 n][256 k] bf16 (mat order Q,K,V,S)
struct PackSrc { const float* w[9]; };
__global__ void k_packall(PackSrc ps, unsigned short* __restrict__ Bt,
                          unsigned short* __restrict__ W1t) {
    int i = blockIdx.x * blockDim.x + threadIdx.x;
    if (i < 524288) {
        int mi = i >> 16;
        int elem = i & 65535;
        int n = elem >> 8, k = elem & 255;
        Bt[i] = f2bf(ps.w[mi][(size_t)k * 256 + n]);
    } else if (i < 524288 + 32768) {
        int e = i - 524288;
        int n = e >> 8, k = e & 255;
        W1t[e] = f2bf(ps.w[8][(size_t)k * 128 + n]);
    }
}

// ---------------- layer 0 projection (IN=2) ----------------
// KV layout: per-row 256 u32, u32[c] = k_c | (v_c << 16)
__global__ __launch_bounds__(256) void k_l0(const float* __restrict__ x,
    const float* __restrict__ Wq, const float* __restrict__ bq,
    const float* __restrict__ Wk, const float* __restrict__ bk,
    const float* __restrict__ Wv, const float* __restrict__ bv,
    const float* __restrict__ Ws, const float* __restrict__ bs,
    float* __restrict__ Q, uint32* __restrict__ KV,
    float* __restrict__ S) {
    int n = blockIdx.x;
    int c = threadIdx.x;
    float x0 = x[n * 2 + 0], x1 = x[n * 2 + 1];
    size_t o = (size_t)n * HCH + c;
    Q[o] = fmaf(x0, Wq[c], fmaf(x1, Wq[HCH + c], bq[c]));
    S[o] = fmaf(x0, Ws[c], fmaf(x1, Ws[HCH + c], bs[c]));
    float kv_ = fmaf(x0, Wk[c], fmaf(x1, Wk[HCH + c], bk[c]));
    float vv_ = fmaf(x0, Wv[c], fmaf(x1, Wv[HCH + c], bv[c]));
    KV[(size_t)n * 256 + c] = (uint32)f2bf(kv_) | ((uint32)f2bf(vv_) << 16);
}

// ---------------- paired projection GEMM ----------------
// Block: 64 rows x 256 cols of TWO matrices sharing the same A strip.
// mode 0: out0=Q fp32, out1=S fp32.  mode 1: out0=KV packed u32 (W0=Wk, W1=Wv).
__global__ __launch_bounds__(256) void k_proj(
    const unsigned short* __restrict__ A,
    const unsigned short* __restrict__ W0, const unsigned short* __restrict__ W1,
    const float* __restrict__ bias0, const float* __restrict__ bias1,
    void* __restrict__ out0, void* __restrict__ out1,
    int M, int mode) {
    __shared__ __align__(16) unsigned short As[64 * 32];
    __shared__ __align__(16) unsigned short Bs0[256 * 32];
    __shared__ __align__(16) unsigned short Bs1[256 * 32];
    const int t = threadIdx.x, wid = t >> 6, l = t & 63;
    const int m0 = blockIdx.x * 64;
    const int srow = l >> 2;
    const int scb = (l & 3) * 16;

    f32x4 acc0[4][4], acc1[4][4];
    #pragma unroll
    for (int m = 0; m < 4; ++m)
        #pragma unroll
        for (int n = 0; n < 4; ++n) { acc0[m][n] = (f32x4)0.f; acc1[m][n] = (f32x4)0.f; }

    const char* Ab = (const char*)A;
    const char* W0b = (const char*)W0;
    const char* W1b = (const char*)W1;

    for (int k0 = 0; k0 < 256; k0 += 32) {
        // A strip chunk: 64 rows x 64B ; wave w stages rows w*16..+15
        __builtin_amdgcn_global_load_lds(
            (const __attribute__((address_space(1))) uint32*)(Ab + (size_t)(m0 + wid * 16 + srow) * 512 + k0 * 2 + scb),
            (__attribute__((address_space(3))) uint32*)((char*)As + wid * 1024), 16, 0, 0);
        // weight chunks: 256 rows x 64B each ; wave w stages rows w*64..+63 (4 calls)
        #pragma unroll
        for (int c = 0; c < 4; ++c) {
            int wrow = wid * 64 + c * 16 + srow;
            __builtin_amdgcn_global_load_lds(
                (const __attribute__((address_space(1))) uint32*)(W0b + (size_t)wrow * 512 + k0 * 2 + scb),
                (__attribute__((address_space(3))) uint32*)((char*)Bs0 + wid * 4096 + c * 1024), 16, 0, 0);
            __builtin_amdgcn_global_load_lds(
                (const __attribute__((address_space(1))) uint32*)(W1b + (size_t)wrow * 512 + k0 * 2 + scb),
                (__attribute__((address_space(3))) uint32*)((char*)Bs1 + wid * 4096 + c * 1024), 16, 0, 0);
        }
        __syncthreads();

        s16x8 af[4], bf[4];
        #pragma unroll
        for (int m = 0; m < 4; ++m)
            af[m] = *(const s16x8*)(As + (size_t)(m * 16 + (l & 15)) * 32 + (l >> 4) * 8);
        #pragma unroll
        for (int n = 0; n < 4; ++n)
            bf[n] = *(const s16x8*)(Bs0 + (size_t)(wid * 64 + n * 16 + (l & 15)) * 32 + (l >> 4) * 8);
        #pragma unroll
        for (int m = 0; m < 4; ++m)
            #pragma unroll
            for (int n = 0; n < 4; ++n)
                acc0[m][n] = __builtin_amdgcn_mfma_f32_16x16x32_bf16(af[m], bf[n], acc0[m][n], 0, 0, 0);
        #pragma unroll
        for (int n = 0; n < 4; ++n)
            bf[n] = *(const s16x8*)(Bs1 + (size_t)(wid * 64 + n * 16 + (l & 15)) * 32 + (l >> 4) * 8);
        #pragma unroll
        for (int m = 0; m < 4; ++m)
            #pragma unroll
            for (int n = 0; n < 4; ++n)
                acc1[m][n] = __builtin_amdgcn_mfma_f32_16x16x32_bf16(af[m], bf[n], acc1[m][n], 0, 0, 0);
        __syncthreads();
    }

    if (mode == 0) {
        float* Qo = (float*)out0;
        float* So = (float*)out1;
        #pragma unroll
        for (int n = 0; n < 4; ++n) {
            int col = wid * 64 + n * 16 + (l & 15);
            float b0 = bias0[col], b1 = bias1[col];
            #pragma unroll
            for (int m = 0; m < 4; ++m) {
                int row0 = m0 + m * 16 + (l >> 4) * 4;
                #pragma unroll
                for (int r = 0; r < 4; ++r) {
                    int row = row0 + r;
                    if (row < M) {
                        Qo[(size_t)row * HCH + col] = acc0[m][n][r] + b0;
                        So[(size_t)row * HCH + col] = acc1[m][n][r] + b1;
                    }
                }
            }
        }
    } else {
        uint32* KVo = (uint32*)out0;
        #pragma unroll
        for (int n = 0; n < 4; ++n) {
            int col = wid * 64 + n * 16 + (l & 15);
            float b0 = bias0[col], b1 = bias1[col];
            #pragma unroll
            for (int m = 0; m < 4; ++m) {
                int row0 = m0 + m * 16 + (l >> 4) * 4;
                #pragma unroll
                for (int r = 0; r < 4; ++r) {
                    int row = row0 + r;
                    if (row < M) {
                        uint32 pk = (uint32)f2bf(acc0[m][n][r] + b0)
                                  | ((uint32)f2bf(acc1[m][n][r] + b1) << 16);
                        KVo[(size_t)row * 256 + col] = pk;
                    }
                }
            }
        }
    }
}

// ---------------- classifier GEMM (fused relu + W2 dot) ----------------
__global__ __launch_bounds__(256) void k_cls(
    const unsigned short* __restrict__ A, const unsigned short* __restrict__ Bt,
    const float* __restrict__ b1, const float* __restrict__ W2,
    const float* __restrict__ b2, float* __restrict__ out, int M) {
    __shared__ __align__(16) unsigned short As[128 * 32];
    __shared__ __align__(16) unsigned short Bs[128 * 32];
    const int t = threadIdx.x, wid = t >> 6, l = t & 63;
    const int m0 = blockIdx.x * 128;
    const int wr = wid >> 1, wc = wid & 1;

    f32x4 acc[4][4];
    #pragma unroll
    for (int m = 0; m < 4; ++m)
        #pragma unroll
        for (int n = 0; n < 4; ++n) acc[m][n] = (f32x4)0.f;

    const int off0 = (wid * 2 + 0) * 1024 + l * 16;
    const int off1 = (wid * 2 + 1) * 1024 + l * 16;
    const int ar0 = off0 >> 6, ac0 = off0 & 63;
    const int ar1 = off1 >> 6, ac1 = off1 & 63;
    const char* Abase = (const char*)A;
    const char* Bbase = (const char*)Bt;
    char* AsB = (char*)As;
    char* BsB = (char*)Bs;

    for (int k0 = 0; k0 < 256; k0 += 32) {
        __builtin_amdgcn_global_load_lds(
            (const __attribute__((address_space(1))) uint32*)(Abase + (size_t)(m0 + ar0) * 512 + k0 * 2 + ac0),
            (__attribute__((address_space(3))) uint32*)(AsB + (wid * 2 + 0) * 1024), 16, 0, 0);
        __builtin_amdgcn_global_load_lds(
            (const __attribute__((address_space(1))) uint32*)(Abase + (size_t)(m0 + ar1) * 512 + k0 * 2 + ac1),
            (__attribute__((address_space(3))) uint32*)(AsB + (wid * 2 + 1) * 1024), 16, 0, 0);
        __builtin_amdgcn_global_load_lds(
            (const __attribute__((address_space(1))) uint32*)(Bbase + (size_t)(ar0)*512 + k0 * 2 + ac0),
            (__attribute__((address_space(3))) uint32*)(BsB + (wid * 2 + 0) * 1024), 16, 0, 0);
        __builtin_amdgcn_global_load_lds(
            (const __attribute__((address_space(1))) uint32*)(Bbase + (size_t)(ar1)*512 + k0 * 2 + ac1),
            (__attribute__((address_space(3))) uint32*)(BsB + (wid * 2 + 1) * 1024), 16, 0, 0);
        __syncthreads();

        s16x8 af[4], bfv[4];
        #pragma unroll
        for (int m = 0; m < 4; ++m)
            af[m] = *(const s16x8*)(As + (size_t)(wr * 64 + m * 16 + (l & 15)) * 32 + (l >> 4) * 8);
        #pragma unroll
        for (int n = 0; n < 4; ++n)
            bfv[n] = *(const s16x8*)(Bs + (size_t)(wc * 64 + n * 16 + (l & 15)) * 32 + (l >> 4) * 8);
        #pragma unroll
        for (int m = 0; m < 4; ++m)
            #pragma unroll
            for (int n = 0; n < 4; ++n)
                acc[m][n] = __builtin_amdgcn_mfma_f32_16x16x32_bf16(af[m], bfv[n], acc[m][n], 0, 0, 0);
        __syncthreads();
    }

    // fused: out[row] = relu(acc + b1) . W2 + b2   (cols 0..127 of hid)
    float w2v[4], bv[4];
    #pragma unroll
    for (int n = 0; n < 4; ++n) {
        int col = wc * 64 + n * 16 + (l & 15);
        w2v[n] = W2[col];
        bv[n] = b1[col];
    }
    float partv[16];
    #pragma unroll
    for (int m = 0; m < 4; ++m)
        #pragma unroll
        for (int r = 0; r < 4; ++r) {
            float pv = 0.f;
            #pragma unroll
            for (int n = 0; n < 4; ++n)
                pv = fmaf(fmaxf(acc[m][n][r] + bv[n], 0.f), w2v[n], pv);
            pv += __shfl_xor(pv, 1); pv += __shfl_xor(pv, 2);
            pv += __shfl_xor(pv, 4); pv += __shfl_xor(pv, 8);
            partv[m * 4 + r] = pv;
        }
    float* cbuf = (float*)As;
    if (wc == 0 && (l & 15) == 0) {
        #pragma unroll
        for (int m = 0; m < 4; ++m)
            #pragma unroll
            for (int r = 0; r < 4; ++r)
                cbuf[wr * 64 + m * 16 + (l >> 4) * 4 + r] = partv[m * 4 + r];
    }
    __syncthreads();
    if (wc == 1 && (l & 15) == 0) {
        float b2v = b2[0];
        #pragma unroll
        for (int m = 0; m < 4; ++m)
            #pragma unroll
            for (int r = 0; r < 4; ++r) {
                int rl = wr * 64 + m * 16 + (l >> 4) * 4 + r;
                int row = m0 + rl;
                if (row < M) out[row] = cbuf[rl] + partv[m * 4 + r] + b2v;
            }
    }
}

// ---------------- fused gather + softmax + aggregate ----------------
__global__ __launch_bounds__(256) void k_agg(
    const float* __restrict__ Q, const unsigned short* __restrict__ KV,
    const float* __restrict__ S,
    const int* __restrict__ off, const int2* __restrict__ csr,
    const float* __restrict__ We,
    unsigned short* __restrict__ Ho, int nnodes) {
    int n = blockIdx.x * 4 + (threadIdx.x >> 6);
    if (n >= nnodes) return;
    int lane = threadIdx.x & 63;
    size_t base = (size_t)n * HCH + lane * 4;
    float4 q = *(const float4*)(Q + base);
    q.x *= 0.125f; q.y *= 0.125f; q.z *= 0.125f; q.w *= 0.125f;
    float4 sk = *(const float4*)(S + base);
    float4 we = *(const float4*)(We + lane * 4);

    float p = q.x * we.x + q.y * we.y + q.z * we.z + q.w * we.w;
    p += __shfl_xor(p, 1); p += __shfl_xor(p, 2);
    p += __shfl_xor(p, 4); p += __shfl_xor(p, 8);
    float qWe = p;

    float ssum = 0.f, accE = 0.f;
    float4 acc = make_float4(0.f, 0.f, 0.f, 0.f);

    int e0 = off[n], e1 = off[n + 1];
    const int laneoff = lane * 8;
    for (int idx = e0; idx < e1; idx += 4) {
        u16x8 kv[4];
        float at[4];
        bool ok[4];
        #pragma unroll
        for (int j = 0; j < 4; ++j) {
            bool o = (idx + j) < e1;
            int2 ee = o ? csr[idx + j] : make_int2(0, 0);
            ok[j] = o;
            at[j] = __int_as_float(ee.y);
            kv[j] = *(const u16x8*)(KV + ((size_t)ee.x << 9) + laneoff);
        }
        #pragma unroll
        for (int j = 0; j < 4; ++j) {
            // layout: kv = [k0 v0 k1 v1 k2 v2 k3 v3]
            float d = q.x * bf2f(kv[j][0]) + q.y * bf2f(kv[j][2])
                    + q.z * bf2f(kv[j][4]) + q.w * bf2f(kv[j][6]);
            d += __shfl_xor(d, 1); d += __shfl_xor(d, 2);
            d += __shfl_xor(d, 4); d += __shfl_xor(d, 8);
            float alpha = fmaf(at[j], qWe, d);
            float w = ok[j] ? __expf(fminf(alpha, 60.f)) : 0.f;
            ssum += w;
            accE = fmaf(w, at[j], accE);
            acc.x = fmaf(w, bf2f(kv[j][1]), acc.x);
            acc.y = fmaf(w, bf2f(kv[j][3]), acc.y);
            acc.z = fmaf(w, bf2f(kv[j][5]), acc.z);
            acc.w = fmaf(w, bf2f(kv[j][7]), acc.w);
        }
    }

    float inv = 1.f / (ssum + 1e-16f);
    ushort4 o;
    o.x = f2bf(fmaxf(fmaf(acc.x + accE * we.x, inv, sk.x), 0.f));
    o.y = f2bf(fmaxf(fmaf(acc.y + accE * we.y, inv, sk.y), 0.f));
    o.z = f2bf(fmaxf(fmaf(acc.z + accE * we.z, inv, sk.z), 0.f));
    o.w = f2bf(fmaxf(fmaf(acc.w + accE * we.w, inv, sk.w), 0.f));
    *(ushort4*)(Ho + base) = o;
}

extern "C" void kernel_launch(void* const* d_in, const int* in_sizes, int n_in,
                              void* d_out, int out_size, void* d_ws, size_t ws_size,
                              hipStream_t stream) {
    const float* x      = (const float*)d_in[0];
    const int*   ei     = (const int*)d_in[1];
    const float* eattr  = (const float*)d_in[2];
    const float* l0_Wq  = (const float*)d_in[3];
    const float* l0_bq  = (const float*)d_in[4];
    const float* l0_Wk  = (const float*)d_in[5];
    const float* l0_bk  = (const float*)d_in[6];
    const float* l0_Wv  = (const float*)d_in[7];
    const float* l0_bv  = (const float*)d_in[8];
    const float* l0_We  = (const float*)d_in[9];
    const float* l0_Wsk = (const float*)d_in[10];
    const float* l0_bsk = (const float*)d_in[11];
    const float* r_Wq   = (const float*)d_in[12];
    const float* r_bq   = (const float*)d_in[13];
    const float* r_Wk   = (const float*)d_in[14];
    const float* r_bk   = (const float*)d_in[15];
    const float* r_Wv   = (const float*)d_in[16];
    const float* r_bv   = (const float*)d_in[17];
    const float* r_We   = (const float*)d_in[18];
    const float* r_Wsk  = (const float*)d_in[19];
    const float* r_bsk  = (const float*)d_in[20];
    const float* cls_W1 = (const float*)d_in[21];
    const float* cls_b1 = (const float*)d_in[22];
    const float* cls_W2 = (const float*)d_in[23];
    const float* cls_b2 = (const float*)d_in[24];
    float* out = (float*)d_out;

    const int* src = ei;
    const int* dst = ei + NE;

    char* p = (char*)d_ws;
    auto alloc = [&](size_t bytes) {
        char* r = p;
        p += (bytes + 255) & ~(size_t)255;
        return r;
    };
    unsigned short* h  = (unsigned short*)alloc((size_t)MPAD * HCH * 2);  // bf16
    float* Qb          = (float*)alloc((size_t)NN * HCH * 4);
    uint32* KV         = (uint32*)alloc((size_t)NN * 256 * 4);            // packed (k,v) u32
    float* Sb          = (float*)alloc((size_t)NN * HCH * 4);
    unsigned short* Bt = (unsigned short*)alloc((size_t)2 * 1024 * 256 * 2);
    unsigned short* W1t= (unsigned short*)alloc((size_t)128 * 256 * 2);
    int* deg      = (int*)alloc((size_t)NN * 4);
    int* incl     = (int*)alloc((size_t)NN * 4);
    int* off      = (int*)alloc((size_t)(NN + 1) * 4);
    int* cur      = (int*)alloc((size_t)NN * 4);
    int* btot     = (int*)alloc(64 * 4);
    int* bbase    = (int*)alloc(64 * 4);
    int2* csr     = (int2*)alloc((size_t)NE * 8);

    const int NB = (NN + 1023) / 1024;   // 49

    // ---- CSR by dst ----
    k_zero<<<(NN + 255) / 256, 256, 0, stream>>>(deg, NN);
    k_hist<<<(NE + 255) / 256, 256, 0, stream>>>(dst, deg, NE);
    k_scan_a<<<NB, 1024, 0, stream>>>(deg, incl, btot, NN);
    k_scan_b<<<1, 64, 0, stream>>>(btot, bbase, NB);
    k_scan_c<<<NB, 1024, 0, stream>>>(deg, incl, bbase, off, cur, NN);
    k_scatter<<<(NE + 255) / 256, 256, 0, stream>>>(src, dst, eattr, cur, csr, NE);

    // ---- pack all weights to bf16 transposed [n][k] in one kernel ----
    PackSrc ps;
    ps.w[0] = r_Wq;  ps.w[1] = r_Wk;  ps.w[2] = r_Wv;  ps.w[3] = r_Wsk;
    ps.w[4] = r_Wq + (size_t)HCH * HCH;  ps.w[5] = r_Wk + (size_t)HCH * HCH;
    ps.w[6] = r_Wv + (size_t)HCH * HCH;  ps.w[7] = r_Wsk + (size_t)HCH * HCH;
    ps.w[8] = cls_W1;
    k_packall<<<(524288 + 32768 + 255) / 256, 256, 0, stream>>>(ps, Bt, W1t);

    // ---- layer 0 ----
    k_l0<<<NN, 256, 0, stream>>>(x, l0_Wq, l0_bq, l0_Wk, l0_bk, l0_Wv, l0_bv,
                                 l0_Wsk, l0_bsk, Qb, KV, Sb);
    k_agg<<<(NN + 3) / 4, 256, 0, stream>>>(Qb, (const unsigned short*)KV, Sb,
                                            off, csr, l0_We, h, NN);

    // ---- layers 1..2 ----
    const int pt = (NN + 63) / 64;    // 782
    const int mt = (NN + 127) / 128;  // 391
    for (int i = 0; i < 2; ++i) {
        const unsigned short* Bi = Bt + (size_t)i * 1024 * 256;
        // Q + S pair (fp32 outputs)
        k_proj<<<pt, 256, 0, stream>>>(h, Bi + 0 * 65536, Bi + 3 * 65536,
                                       r_bq + (size_t)i * HCH, r_bsk + (size_t)i * HCH,
                                       Qb, Sb, NN, 0);
        // K + V pair (packed u32 output)
        k_proj<<<pt, 256, 0, stream>>>(h, Bi + 1 * 65536, Bi + 2 * 65536,
                                       r_bk + (size_t)i * HCH, r_bv + (size_t)i * HCH,
                                       KV, nullptr, NN, 1);
        k_agg<<<(NN + 3) / 4, 256, 0, stream>>>(Qb, (const unsigned short*)KV, Sb,
                                                off, csr, r_We + (size_t)i * HCH, h, NN);
    }

    // ---- classifier ----
    k_cls<<<mt, 256, 0, stream>>>(h, W1t, cls_b1, cls_W2, cls_b2, out, NN);
}

// Round 5
// 650.962 us; speedup vs baseline: 1.2514x; 1.2514x over previous
//
#include <hip/hip_runtime.h>
#include <cstddef>

#define NN 50000
#define NE 800000
#define HCH 256     // H*C
#define MPAD 50048  // 391*128

typedef __attribute__((ext_vector_type(4))) float f32x4;
typedef __attribute__((ext_vector_type(8))) short s16x8;
typedef __attribute__((ext_vector_type(8))) unsigned short u16x8;
typedef unsigned int uint32;

__device__ inline float bf2f(unsigned short u) {
    return __uint_as_float(((unsigned int)u) << 16);
}
__device__ inline unsigned short f2bf(float f) {
    unsigned int x = __float_as_uint(f);
    x += 0x7FFFu + ((x >> 16) & 1u);   // round to nearest even
    return (unsigned short)(x >> 16);
}

// ---------------- CSR build ----------------
__global__ void k_zero(int* __restrict__ p, int n) {
    int i = blockIdx.x * blockDim.x + threadIdx.x;
    if (i < n) p[i] = 0;
}

__global__ void k_hist(const int* __restrict__ dst, int* __restrict__ deg, int e) {
    int i = blockIdx.x * blockDim.x + threadIdx.x;
    if (i < e) atomicAdd(&deg[dst[i]], 1);
}

__global__ __launch_bounds__(1024) void k_scan_a(const int* __restrict__ deg,
                                                 int* __restrict__ incl,
                                                 int* __restrict__ btot, int n) {
    __shared__ int buf[1024];
    int t = threadIdx.x;
    int i = blockIdx.x * 1024 + t;
    int v = (i < n) ? deg[i] : 0;
    buf[t] = v;
    __syncthreads();
    #pragma unroll
    for (int s = 1; s < 1024; s <<= 1) {
        int tv = (t >= s) ? buf[t - s] : 0;
        __syncthreads();
        buf[t] += tv;
        __syncthreads();
    }
    if (i < n) incl[i] = buf[t];
    if (t == 1023) btot[blockIdx.x] = buf[1023];
}

__global__ void k_scan_b(const int* __restrict__ btot, int* __restrict__ bbase, int nb) {
    if (threadIdx.x == 0 && blockIdx.x == 0) {
        int s = 0;
        for (int b = 0; b < nb; ++b) { bbase[b] = s; s += btot[b]; }
    }
}

__global__ __launch_bounds__(1024) void k_scan_c(const int* __restrict__ deg,
                                                 const int* __restrict__ incl,
                                                 const int* __restrict__ bbase,
                                                 int* __restrict__ off,
                                                 int* __restrict__ cur, int n) {
    int i = blockIdx.x * 1024 + threadIdx.x;
    if (i < n) {
        int inc = bbase[blockIdx.x] + incl[i];
        off[i + 1] = inc;
        cur[i] = inc - deg[i];
    }
    if (i == 0) off[0] = 0;
}

__global__ void k_scatter(const int* __restrict__ src, const int* __restrict__ dst,
                          const float* __restrict__ attr, int* __restrict__ cur,
                          int2* __restrict__ csr, int e) {
    int i = blockIdx.x * blockDim.x + threadIdx.x;
    if (i < e) {
        int d = dst[i];
        int pos = atomicAdd(&cur[d], 1);
        csr[pos] = make_int2(src[i], __float_as_int(attr[i]));
    }
}

// ---------------- fused weight pack: 8 layer mats + classifier W1 ----------------
// Bt layout: [layer*4 + mat][256 n][256 k] bf16 (mat order Q,K,V,S)
struct PackSrc { const float* w[9]; };
__global__ void k_packall(PackSrc ps, unsigned short* __restrict__ Bt,
                          unsigned short* __restrict__ W1t) {
    int i = blockIdx.x * blockDim.x + threadIdx.x;
    if (i < 524288) {
        int mi = i >> 16;
        int elem = i & 65535;
        int n = elem >> 8, k = elem & 255;
        Bt[i] = f2bf(ps.w[mi][(size_t)k * 256 + n]);
    } else if (i < 524288 + 32768) {
        int e = i - 524288;
        int n = e >> 8, k = e & 255;
        W1t[e] = f2bf(ps.w[8][(size_t)k * 128 + n]);
    }
}

// ---------------- layer 0 projection (IN=2), all-bf16 outputs ----------------
__global__ __launch_bounds__(256) void k_l0(const float* __restrict__ x,
    const float* __restrict__ Wq, const float* __restrict__ bq,
    const float* __restrict__ Wk, const float* __restrict__ bk,
    const float* __restrict__ Wv, const float* __restrict__ bv,
    const float* __restrict__ Ws, const float* __restrict__ bs,
    unsigned short* __restrict__ Q, unsigned short* __restrict__ K,
    unsigned short* __restrict__ V, unsigned short* __restrict__ S) {
    int n = blockIdx.x;
    int c = threadIdx.x;
    float x0 = x[n * 2 + 0], x1 = x[n * 2 + 1];
    size_t o = (size_t)n * HCH + c;
    Q[o] = f2bf(fmaf(x0, Wq[c], fmaf(x1, Wq[HCH + c], bq[c])));
    S[o] = f2bf(fmaf(x0, Ws[c], fmaf(x1, Ws[HCH + c], bs[c])));
    K[o] = f2bf(fmaf(x0, Wk[c], fmaf(x1, Wk[HCH + c], bk[c])));
    V[o] = f2bf(fmaf(x0, Wv[c], fmaf(x1, Wv[HCH + c], bv[c])));
}

// ---------------- unified 4-matrix MFMA GEMM ----------------
// 1D grid 3128 = 391 row-tiles x 8 col-groups, bijective XCD swizzle:
// xcd = blk%8 owns virtual ids v = xcd*391 + blk/8; row = v/8, colgrp = v%8.
// All outputs bf16, contiguous [row][256].
struct GOut4 {
    unsigned short* o[4];
    const float* b[4];
};

__global__ __launch_bounds__(256) void k_mfma4(
    const unsigned short* __restrict__ A, const unsigned short* __restrict__ Bt,
    GOut4 g, int M) {
    __shared__ __align__(16) unsigned short As[128 * 32];
    __shared__ __align__(16) unsigned short Bs[128 * 32];
    const int t = threadIdx.x, wid = t >> 6, l = t & 63;
    const int v = (blockIdx.x & 7) * 391 + (blockIdx.x >> 3);
    const int m0 = (v >> 3) * 128;
    const int n0 = (v & 7) * 128;
    const int wr = wid >> 1, wc = wid & 1;

    f32x4 acc[4][4];
    #pragma unroll
    for (int m = 0; m < 4; ++m)
        #pragma unroll
        for (int n = 0; n < 4; ++n) acc[m][n] = (f32x4)0.f;

    const int off0 = (wid * 2 + 0) * 1024 + l * 16;
    const int off1 = (wid * 2 + 1) * 1024 + l * 16;
    const int ar0 = off0 >> 6, ac0 = off0 & 63;
    const int ar1 = off1 >> 6, ac1 = off1 & 63;
    const char* Abase = (const char*)A;
    const char* Bbase = (const char*)Bt;
    char* AsB = (char*)As;
    char* BsB = (char*)Bs;

    for (int k0 = 0; k0 < 256; k0 += 32) {
        __builtin_amdgcn_global_load_lds(
            (const __attribute__((address_space(1))) uint32*)(Abase + (size_t)(m0 + ar0) * 512 + k0 * 2 + ac0),
            (__attribute__((address_space(3))) uint32*)(AsB + (wid * 2 + 0) * 1024), 16, 0, 0);
        __builtin_amdgcn_global_load_lds(
            (const __attribute__((address_space(1))) uint32*)(Abase + (size_t)(m0 + ar1) * 512 + k0 * 2 + ac1),
            (__attribute__((address_space(3))) uint32*)(AsB + (wid * 2 + 1) * 1024), 16, 0, 0);
        __builtin_amdgcn_global_load_lds(
            (const __attribute__((address_space(1))) uint32*)(Bbase + (size_t)(n0 + ar0) * 512 + k0 * 2 + ac0),
            (__attribute__((address_space(3))) uint32*)(BsB + (wid * 2 + 0) * 1024), 16, 0, 0);
        __builtin_amdgcn_global_load_lds(
            (const __attribute__((address_space(1))) uint32*)(Bbase + (size_t)(n0 + ar1) * 512 + k0 * 2 + ac1),
            (__attribute__((address_space(3))) uint32*)(BsB + (wid * 2 + 1) * 1024), 16, 0, 0);
        __syncthreads();

        s16x8 af[4], bfv[4];
        #pragma unroll
        for (int m = 0; m < 4; ++m)
            af[m] = *(const s16x8*)(As + (size_t)(wr * 64 + m * 16 + (l & 15)) * 32 + (l >> 4) * 8);
        #pragma unroll
        for (int n = 0; n < 4; ++n)
            bfv[n] = *(const s16x8*)(Bs + (size_t)(wc * 64 + n * 16 + (l & 15)) * 32 + (l >> 4) * 8);
        #pragma unroll
        for (int m = 0; m < 4; ++m)
            #pragma unroll
            for (int n = 0; n < 4; ++n)
                acc[m][n] = __builtin_amdgcn_mfma_f32_16x16x32_bf16(af[m], bfv[n], acc[m][n], 0, 0, 0);
        __syncthreads();
    }

    const int mat = n0 >> 8;
    const int colBase = (n0 & 255) + wc * 64;
    const float* bias = g.b[mat];
    unsigned short* O = g.o[mat];
    #pragma unroll
    for (int n = 0; n < 4; ++n) {
        int col = colBase + n * 16 + (l & 15);
        float bv = bias[col];
        #pragma unroll
        for (int m = 0; m < 4; ++m) {
            int row0 = m0 + wr * 64 + m * 16 + (l >> 4) * 4;
            #pragma unroll
            for (int r = 0; r < 4; ++r) {
                int row = row0 + r;
                if (row < M)
                    O[(size_t)row * HCH + col] = f2bf(acc[m][n][r] + bv);
            }
        }
    }
}

// ---------------- classifier GEMM (fused relu + W2 dot) ----------------
__global__ __launch_bounds__(256) void k_cls(
    const unsigned short* __restrict__ A, const unsigned short* __restrict__ Bt,
    const float* __restrict__ b1, const float* __restrict__ W2,
    const float* __restrict__ b2, float* __restrict__ out, int M) {
    __shared__ __align__(16) unsigned short As[128 * 32];
    __shared__ __align__(16) unsigned short Bs[128 * 32];
    const int t = threadIdx.x, wid = t >> 6, l = t & 63;
    const int m0 = blockIdx.x * 128;
    const int wr = wid >> 1, wc = wid & 1;

    f32x4 acc[4][4];
    #pragma unroll
    for (int m = 0; m < 4; ++m)
        #pragma unroll
        for (int n = 0; n < 4; ++n) acc[m][n] = (f32x4)0.f;

    const int off0 = (wid * 2 + 0) * 1024 + l * 16;
    const int off1 = (wid * 2 + 1) * 1024 + l * 16;
    const int ar0 = off0 >> 6, ac0 = off0 & 63;
    const int ar1 = off1 >> 6, ac1 = off1 & 63;
    const char* Abase = (const char*)A;
    const char* Bbase = (const char*)Bt;
    char* AsB = (char*)As;
    char* BsB = (char*)Bs;

    for (int k0 = 0; k0 < 256; k0 += 32) {
        __builtin_amdgcn_global_load_lds(
            (const __attribute__((address_space(1))) uint32*)(Abase + (size_t)(m0 + ar0) * 512 + k0 * 2 + ac0),
            (__attribute__((address_space(3))) uint32*)(AsB + (wid * 2 + 0) * 1024), 16, 0, 0);
        __builtin_amdgcn_global_load_lds(
            (const __attribute__((address_space(1))) uint32*)(Abase + (size_t)(m0 + ar1) * 512 + k0 * 2 + ac1),
            (__attribute__((address_space(3))) uint32*)(AsB + (wid * 2 + 1) * 1024), 16, 0, 0);
        __builtin_amdgcn_global_load_lds(
            (const __attribute__((address_space(1))) uint32*)(Bbase + (size_t)(ar0)*512 + k0 * 2 + ac0),
            (__attribute__((address_space(3))) uint32*)(BsB + (wid * 2 + 0) * 1024), 16, 0, 0);
        __builtin_amdgcn_global_load_lds(
            (const __attribute__((address_space(1))) uint32*)(Bbase + (size_t)(ar1)*512 + k0 * 2 + ac1),
            (__attribute__((address_space(3))) uint32*)(BsB + (wid * 2 + 1) * 1024), 16, 0, 0);
        __syncthreads();

        s16x8 af[4], bfv[4];
        #pragma unroll
        for (int m = 0; m < 4; ++m)
            af[m] = *(const s16x8*)(As + (size_t)(wr * 64 + m * 16 + (l & 15)) * 32 + (l >> 4) * 8);
        #pragma unroll
        for (int n = 0; n < 4; ++n)
            bfv[n] = *(const s16x8*)(Bs + (size_t)(wc * 64 + n * 16 + (l & 15)) * 32 + (l >> 4) * 8);
        #pragma unroll
        for (int m = 0; m < 4; ++m)
            #pragma unroll
            for (int n = 0; n < 4; ++n)
                acc[m][n] = __builtin_amdgcn_mfma_f32_16x16x32_bf16(af[m], bfv[n], acc[m][n], 0, 0, 0);
        __syncthreads();
    }

    float w2v[4], bv[4];
    #pragma unroll
    for (int n = 0; n < 4; ++n) {
        int col = wc * 64 + n * 16 + (l & 15);
        w2v[n] = W2[col];
        bv[n] = b1[col];
    }
    float partv[16];
    #pragma unroll
    for (int m = 0; m < 4; ++m)
        #pragma unroll
        for (int r = 0; r < 4; ++r) {
            float pv = 0.f;
            #pragma unroll
            for (int n = 0; n < 4; ++n)
                pv = fmaf(fmaxf(acc[m][n][r] + bv[n], 0.f), w2v[n], pv);
            pv += __shfl_xor(pv, 1); pv += __shfl_xor(pv, 2);
            pv += __shfl_xor(pv, 4); pv += __shfl_xor(pv, 8);
            partv[m * 4 + r] = pv;
        }
    float* cbuf = (float*)As;
    if (wc == 0 && (l & 15) == 0) {
        #pragma unroll
        for (int m = 0; m < 4; ++m)
            #pragma unroll
            for (int r = 0; r < 4; ++r)
                cbuf[wr * 64 + m * 16 + (l >> 4) * 4 + r] = partv[m * 4 + r];
    }
    __syncthreads();
    if (wc == 1 && (l & 15) == 0) {
        float b2v = b2[0];
        #pragma unroll
        for (int m = 0; m < 4; ++m)
            #pragma unroll
            for (int r = 0; r < 4; ++r) {
                int rl = wr * 64 + m * 16 + (l >> 4) * 4 + r;
                int row = m0 + rl;
                if (row < M) out[row] = cbuf[rl] + partv[m * 4 + r] + b2v;
            }
    }
}

// ---------------- fused gather + softmax + aggregate (all-bf16 inputs) ----------------
__global__ __launch_bounds__(256) void k_agg(
    const unsigned short* __restrict__ Q, const unsigned short* __restrict__ K,
    const unsigned short* __restrict__ V, const unsigned short* __restrict__ S,
    const int* __restrict__ off, const int2* __restrict__ csr,
    const float* __restrict__ We,
    unsigned short* __restrict__ Ho, int nnodes) {
    int n = blockIdx.x * 4 + (threadIdx.x >> 6);
    if (n >= nnodes) return;
    int lane = threadIdx.x & 63;
    size_t base = (size_t)n * HCH + lane * 4;
    ushort4 qu = *(const ushort4*)(Q + base);
    ushort4 su = *(const ushort4*)(S + base);
    float4 q = make_float4(bf2f(qu.x) * 0.125f, bf2f(qu.y) * 0.125f,
                           bf2f(qu.z) * 0.125f, bf2f(qu.w) * 0.125f);
    float4 sk = make_float4(bf2f(su.x), bf2f(su.y), bf2f(su.z), bf2f(su.w));
    float4 we = *(const float4*)(We + lane * 4);

    float p = q.x * we.x + q.y * we.y + q.z * we.z + q.w * we.w;
    p += __shfl_xor(p, 1); p += __shfl_xor(p, 2);
    p += __shfl_xor(p, 4); p += __shfl_xor(p, 8);
    float qWe = p;

    float ssum = 0.f, accE = 0.f;
    float4 acc = make_float4(0.f, 0.f, 0.f, 0.f);

    int e0 = off[n], e1 = off[n + 1];
    const int laneoff = lane * 4;
    for (int idx = e0; idx < e1; idx += 4) {
        ushort4 ku[4], vu[4];
        float at[4];
        bool ok[4];
        #pragma unroll
        for (int j = 0; j < 4; ++j) {
            bool o = (idx + j) < e1;
            int2 ee = o ? csr[idx + j] : make_int2(0, 0);
            ok[j] = o;
            at[j] = __int_as_float(ee.y);
            size_t sb = ((size_t)ee.x << 8) + laneoff;
            ku[j] = *(const ushort4*)(K + sb);
            vu[j] = *(const ushort4*)(V + sb);
        }
        #pragma unroll
        for (int j = 0; j < 4; ++j) {
            float d = q.x * bf2f(ku[j].x) + q.y * bf2f(ku[j].y)
                    + q.z * bf2f(ku[j].z) + q.w * bf2f(ku[j].w);
            d += __shfl_xor(d, 1); d += __shfl_xor(d, 2);
            d += __shfl_xor(d, 4); d += __shfl_xor(d, 8);
            float alpha = fmaf(at[j], qWe, d);
            float w = ok[j] ? __expf(fminf(alpha, 60.f)) : 0.f;
            ssum += w;
            accE = fmaf(w, at[j], accE);
            acc.x = fmaf(w, bf2f(vu[j].x), acc.x);
            acc.y = fmaf(w, bf2f(vu[j].y), acc.y);
            acc.z = fmaf(w, bf2f(vu[j].z), acc.z);
            acc.w = fmaf(w, bf2f(vu[j].w), acc.w);
        }
    }

    float inv = 1.f / (ssum + 1e-16f);
    ushort4 o;
    o.x = f2bf(fmaxf(fmaf(acc.x + accE * we.x, inv, sk.x), 0.f));
    o.y = f2bf(fmaxf(fmaf(acc.y + accE * we.y, inv, sk.y), 0.f));
    o.z = f2bf(fmaxf(fmaf(acc.z + accE * we.z, inv, sk.z), 0.f));
    o.w = f2bf(fmaxf(fmaf(acc.w + accE * we.w, inv, sk.w), 0.f));
    *(ushort4*)(Ho + base) = o;
}

extern "C" void kernel_launch(void* const* d_in, const int* in_sizes, int n_in,
                              void* d_out, int out_size, void* d_ws, size_t ws_size,
                              hipStream_t stream) {
    const float* x      = (const float*)d_in[0];
    const int*   ei     = (const int*)d_in[1];
    const float* eattr  = (const float*)d_in[2];
    const float* l0_Wq  = (const float*)d_in[3];
    const float* l0_bq  = (const float*)d_in[4];
    const float* l0_Wk  = (const float*)d_in[5];
    const float* l0_bk  = (const float*)d_in[6];
    const float* l0_Wv  = (const float*)d_in[7];
    const float* l0_bv  = (const float*)d_in[8];
    const float* l0_We  = (const float*)d_in[9];
    const float* l0_Wsk = (const float*)d_in[10];
    const float* l0_bsk = (const float*)d_in[11];
    const float* r_Wq   = (const float*)d_in[12];
    const float* r_bq   = (const float*)d_in[13];
    const float* r_Wk   = (const float*)d_in[14];
    const float* r_bk   = (const float*)d_in[15];
    const float* r_Wv   = (const float*)d_in[16];
    const float* r_bv   = (const float*)d_in[17];
    const float* r_We   = (const float*)d_in[18];
    const float* r_Wsk  = (const float*)d_in[19];
    const float* r_bsk  = (const float*)d_in[20];
    const float* cls_W1 = (const float*)d_in[21];
    const float* cls_b1 = (const float*)d_in[22];
    const float* cls_W2 = (const float*)d_in[23];
    const float* cls_b2 = (const float*)d_in[24];
    float* out = (float*)d_out;

    const int* src = ei;
    const int* dst = ei + NE;

    char* p = (char*)d_ws;
    auto alloc = [&](size_t bytes) {
        char* r = p;
        p += (bytes + 255) & ~(size_t)255;
        return r;
    };
    unsigned short* h  = (unsigned short*)alloc((size_t)MPAD * HCH * 2);
    unsigned short* Qb = (unsigned short*)alloc((size_t)NN * HCH * 2);
    unsigned short* Kb = (unsigned short*)alloc((size_t)NN * HCH * 2);
    unsigned short* Vb = (unsigned short*)alloc((size_t)NN * HCH * 2);
    unsigned short* Sb = (unsigned short*)alloc((size_t)NN * HCH * 2);
    unsigned short* Bt = (unsigned short*)alloc((size_t)2 * 1024 * 256 * 2);
    unsigned short* W1t= (unsigned short*)alloc((size_t)128 * 256 * 2);
    int* deg      = (int*)alloc((size_t)NN * 4);
    int* incl     = (int*)alloc((size_t)NN * 4);
    int* off      = (int*)alloc((size_t)(NN + 1) * 4);
    int* cur      = (int*)alloc((size_t)NN * 4);
    int* btot     = (int*)alloc(64 * 4);
    int* bbase    = (int*)alloc(64 * 4);
    int2* csr     = (int2*)alloc((size_t)NE * 8);

    const int NB = (NN + 1023) / 1024;   // 49

    // ---- CSR by dst ----
    k_zero<<<(NN + 255) / 256, 256, 0, stream>>>(deg, NN);
    k_hist<<<(NE + 255) / 256, 256, 0, stream>>>(dst, deg, NE);
    k_scan_a<<<NB, 1024, 0, stream>>>(deg, incl, btot, NN);
    k_scan_b<<<1, 64, 0, stream>>>(btot, bbase, NB);
    k_scan_c<<<NB, 1024, 0, stream>>>(deg, incl, bbase, off, cur, NN);
    k_scatter<<<(NE + 255) / 256, 256, 0, stream>>>(src, dst, eattr, cur, csr, NE);

    // ---- pack all weights to bf16 transposed [n][k] ----
    PackSrc ps;
    ps.w[0] = r_Wq;  ps.w[1] = r_Wk;  ps.w[2] = r_Wv;  ps.w[3] = r_Wsk;
    ps.w[4] = r_Wq + (size_t)HCH * HCH;  ps.w[5] = r_Wk + (size_t)HCH * HCH;
    ps.w[6] = r_Wv + (size_t)HCH * HCH;  ps.w[7] = r_Wsk + (size_t)HCH * HCH;
    ps.w[8] = cls_W1;
    k_packall<<<(524288 + 32768 + 255) / 256, 256, 0, stream>>>(ps, Bt, W1t);

    // ---- layer 0 ----
    k_l0<<<NN, 256, 0, stream>>>(x, l0_Wq, l0_bq, l0_Wk, l0_bk, l0_Wv, l0_bv,
                                 l0_Wsk, l0_bsk, Qb, Kb, Vb, Sb);
    k_agg<<<(NN + 3) / 4, 256, 0, stream>>>(Qb, Kb, Vb, Sb, off, csr, l0_We, h, NN);

    // ---- layers 1..2 ----
    const int mt = (NN + 127) / 128;  // 391
    for (int i = 0; i < 2; ++i) {
        const unsigned short* Bi = Bt + (size_t)i * 1024 * 256;
        GOut4 g;
        g.o[0] = Qb; g.b[0] = r_bq + (size_t)i * HCH;
        g.o[1] = Kb; g.b[1] = r_bk + (size_t)i * HCH;
        g.o[2] = Vb; g.b[2] = r_bv + (size_t)i * HCH;
        g.o[3] = Sb; g.b[3] = r_bsk + (size_t)i * HCH;
        k_mfma4<<<mt * 8, 256, 0, stream>>>(h, Bi, g, NN);
        k_agg<<<(NN + 3) / 4, 256, 0, stream>>>(Qb, Kb, Vb, Sb, off, csr,
                                                r_We + (size_t)i * HCH, h, NN);
    }

    // ---- classifier ----
    k_cls<<<mt, 256, 0, stream>>>(h, W1t, cls_b1, cls_W2, cls_b2, out, NN);
}